// Round 15
// baseline (239.887 us; speedup 1.0000x reference)
//
#include <hip/hip_runtime.h>

// Inputs/outputs fp32; internal compute bf16 MFMA (bf16-grade comparison).
// ws layout (64 MB):
//   [0,16M)   Yp    fp32 [B,S,D]
//   [16M,24M) Xb    bf16 [B*S, D]
//   [24M,30M) Wcat  bf16 [3072,1024]
//   [30M,32M) Wob   bf16 [1024,1024]
//   [32M,40M) Qb    bf16 [B,H,S,DK] (post-PE, pre-scaled by 0.125/ln2)
//   [40M,48M) Kraw  bf16 [B,H,S,DK] -> reused as Ab bf16 [B,S,D] after ema_pe
//   [48M,56M) Kp    bf16 packed K-frag order [bh][kt16][c][lane][j8]
//   [56M,64M) Vp    bf16 packed V^T-frag order [bh][kb64][t*4+dn][lane][j4]

#define LB __launch_bounds__(256)
// r6/r8 lesson: NO min-waves hint on attn (VGPR squeeze kills load batching).
// r10 lesson: NO loop-carried MFMA accumulator chains.
// r14 lesson: attn is L2-BW bound (~18 of 34.5 TB/s) — reuse K/V across 2
// q-tiles per wave (r6 retried with grid 2048 + split-K, the real r6 bugs).

typedef unsigned short u16;
typedef unsigned int u32;
typedef __attribute__((ext_vector_type(2))) unsigned int u32x2;
typedef __attribute__((ext_vector_type(4))) unsigned short us4;
typedef __attribute__((ext_vector_type(8))) unsigned short us8;
typedef __attribute__((ext_vector_type(8))) __bf16 bf8;
typedef __attribute__((ext_vector_type(4))) float f4;
typedef __attribute__((ext_vector_type(4))) short s4;

// softmax scale folded into Q: exp(s/8) = exp2(s * 0.125/ln2)
#define QSCALE 0.18033688011112042f

#if __has_builtin(__builtin_amdgcn_exp2f)
#define EXP2 __builtin_amdgcn_exp2f   // raw v_exp_f32, no denorm fixup
#else
#define EXP2 exp2f
#endif

static __device__ __forceinline__ float bf2f(u16 h) {
  union { unsigned int u; float f; } c; c.u = ((unsigned int)h) << 16; return c.f;
}
static __device__ __forceinline__ u16 f2bf(float f) {
  union { float f; unsigned int u; } c; c.f = f;
  unsigned int u = c.u + 0x7FFFu + ((c.u >> 16) & 1u);
  return (u16)(u >> 16);
}
#if __has_builtin(__builtin_amdgcn_cvt_pk_bf16_f32)
typedef __attribute__((ext_vector_type(2))) __bf16 bf2v;
static __device__ __forceinline__ us4 pk_bf16x4(f4 v) {
  bf2v lo = __builtin_amdgcn_cvt_pk_bf16_f32(v[0], v[1]);
  bf2v hi = __builtin_amdgcn_cvt_pk_bf16_f32(v[2], v[3]);
  u32x2 r = {__builtin_bit_cast(u32, lo), __builtin_bit_cast(u32, hi)};
  return __builtin_bit_cast(us4, r);
}
#else
static __device__ __forceinline__ us4 pk_bf16x4(f4 v) {
  return us4{f2bf(v[0]), f2bf(v[1]), f2bf(v[2]), f2bf(v[3])};
}
#endif
static __device__ __forceinline__ float pe_val(int s, int dk) {
  float fr = __expf((float)(dk & ~1) * (-9.210340371976184f / 64.0f));
  float ang = (float)s * fr;
  return (dk & 1) ? __cosf(ang) : __sinf(ang);
}

// 16x16x16 bf16 MFMA, hedged across builtin generations (verified r5).
#if __has_builtin(__builtin_amdgcn_mfma_f32_16x16x16bf16_1k)
static __device__ __forceinline__ f4 mfma16(us4 a, us4 b, f4 c) {
  return __builtin_amdgcn_mfma_f32_16x16x16bf16_1k(
      __builtin_bit_cast(s4, a), __builtin_bit_cast(s4, b), c, 0, 0, 0);
}
#elif __has_builtin(__builtin_amdgcn_mfma_f32_16x16x16_bf16)
typedef __attribute__((ext_vector_type(4))) __bf16 bf4;
static __device__ __forceinline__ f4 mfma16(us4 a, us4 b, f4 c) {
  return __builtin_amdgcn_mfma_f32_16x16x16_bf16(
      __builtin_bit_cast(bf4, a), __builtin_bit_cast(bf4, b), c, 0, 0, 0);
}
#else
static __device__ __forceinline__ f4 mfma16(us4 a, us4 b, f4 c) {
  asm volatile("v_mfma_f32_16x16x16_bf16 %0, %1, %2, %0" : "+v"(c) : "v"(a), "v"(b));
  return c;
}
#endif

#define GLDS(gp, lp) __builtin_amdgcn_global_load_lds( \
    (const __attribute__((address_space(1))) void*)(gp), \
    (__attribute__((address_space(3))) void*)(lp), 16, 0, 0)

// ---------------- fp32 -> bf16 conversion pre-pass ----------------
__global__ LB void cvt_kernel(const float* __restrict__ X, const float* __restrict__ Wq,
                              const float* __restrict__ Wk, const float* __restrict__ Wv,
                              const float* __restrict__ Wo, u16* __restrict__ Xb,
                              u16* __restrict__ Wcat, u16* __restrict__ Wob) {
  const unsigned t = blockIdx.x * 256 + threadIdx.x;
  const float* src; u16* dst; size_t off;
  if (t < (512u << 10))      { src = X;  dst = Xb;                off = t; }
  else if (t < (640u << 10)) { src = Wq; dst = Wcat;              off = t - (512u << 10); }
  else if (t < (768u << 10)) { src = Wk; dst = Wcat + (1u << 20); off = t - (640u << 10); }
  else if (t < (896u << 10)) { src = Wv; dst = Wcat + (2u << 20); off = t - (768u << 10); }
  else                       { src = Wo; dst = Wob;               off = t - (896u << 10); }
  off *= 8;
  f4 a = *(const f4*)(src + off);
  f4 b = *(const f4*)(src + off + 4);
  us8 o = {f2bf(a[0]), f2bf(a[1]), f2bf(a[2]), f2bf(a[3]),
           f2bf(b[0]), f2bf(b[1]), f2bf(b[2]), f2bf(b[3])};
  *(us8*)(dst + off) = o;
}

// ---------------- m97-style GEMM core ----------------
static __device__ __forceinline__ void gemm_core(
    const u16* __restrict__ Abase, const u16* __restrict__ Bbase,
    u16* Als, u16* Bls, int m0, int n0, int tid, f4 acc[4][4]) {
  const int w = tid >> 6, lane = tid & 63;
  const int l16 = lane & 15, quad = lane >> 4;
  const int wm = w & 1, wn = w >> 1;
  for (int kk = 0; kk < 1024; kk += 32) {
    __syncthreads();
#pragma unroll
    for (int it = 0; it < 2; it++) {
      int cb = (w * 2 + it) * 64;
      int c = cb + lane;
      int row = c >> 2, kc = c & 3;
      GLDS(Abase + (size_t)(m0 + row) * 1024 + kk + kc * 8, &Als[cb * 8]);
      GLDS(Bbase + (size_t)(n0 + row) * 1024 + kk + kc * 8, &Bls[cb * 8]);
    }
    __syncthreads();
    bf8 af[4], bfr[4];
#pragma unroll
    for (int mt = 0; mt < 4; mt++)
      af[mt] = __builtin_bit_cast(bf8, *(const us8*)(&Als[(wm * 64 + mt * 16 + l16) * 32 + quad * 8]));
#pragma unroll
    for (int nt = 0; nt < 4; nt++)
      bfr[nt] = __builtin_bit_cast(bf8, *(const us8*)(&Bls[(wn * 64 + nt * 16 + l16) * 32 + quad * 8]));
#pragma unroll
    for (int mt = 0; mt < 4; mt++)
#pragma unroll
      for (int nt = 0; nt < 4; nt++)
        acc[mt][nt] = __builtin_amdgcn_mfma_f32_16x16x32_bf16(af[mt], bfr[nt], acc[mt][nt], 0, 0, 0);
  }
}

// ---------------- QKV projection (fused N=3072) ----------------
__global__ LB void gemm_qkv(const u16* __restrict__ Xb, const u16* __restrict__ Wcat,
                            u16* __restrict__ Qb, u16* __restrict__ Kraw,
                            u16* __restrict__ Vp) {
  __shared__ u16 Als[128 * 32];
  __shared__ u16 Bls[128 * 32];
  const int tid = threadIdx.x;
  const int m0 = blockIdx.y * 128, n0 = blockIdx.x * 128;
  f4 acc[4][4];
#pragma unroll
  for (int a = 0; a < 4; a++)
#pragma unroll
    for (int b = 0; b < 4; b++) acc[a][b] = f4{0.f, 0.f, 0.f, 0.f};
  gemm_core(Xb, Wcat, Als, Bls, m0, n0, tid, acc);

  const int w = tid >> 6, lane = tid & 63;
  const int l16 = lane & 15, quad = lane >> 4;
  const int wm = w & 1, wn = w >> 1;
  const int z = blockIdx.x >> 3;  // 0:Q 1:K 2:V
  if (z == 2) {
    const int b = m0 >> 11;
    const int hh = ((n0 + wn * 64) & 1023) >> 6;        // parens! (r13 bug)
    const size_t bhoff = (size_t)(b * 16 + hh) * (2048 * 64);
#pragma unroll
    for (int mt = 0; mt < 4; mt++) {
      int sb = (m0 & 2047) + wm * 64 + mt * 16;
      int kb = sb >> 6;
      int t  = (sb >> 4) & 3;
#pragma unroll
      for (int nt = 0; nt < 4; nt++) {
        size_t o = bhoff + (size_t)kb * 4096 +
                   (size_t)(((t * 4 + nt) * 64 + quad * 16 + l16) * 4);
        *(us4*)(Vp + o) = pk_bf16x4(acc[mt][nt]);  // r=0..3 contiguous
      }
    }
  } else {
#pragma unroll
    for (int mt = 0; mt < 4; mt++)
#pragma unroll
      for (int nt = 0; nt < 4; nt++)
#pragma unroll
        for (int r = 0; r < 4; r++) {
          int m = m0 + wm * 64 + mt * 16 + quad * 4 + r;
          int nn = (n0 + wn * 64 + nt * 16 + l16) & 1023;
          float v = acc[mt][nt][r];
          int b = m >> 11, s = m & 2047, h = nn >> 6, dk = nn & 63;
          size_t bhoff = (size_t)(b * 16 + h) * (2048 * 64);
          if (z == 0) {
            Qb[bhoff + (size_t)s * 64 + dk] = f2bf((v + pe_val(s, dk)) * QSCALE);
          } else {
            Kraw[bhoff + (size_t)s * 64 + dk] = f2bf(v);
          }
        }
  }
}

// ---------------- EMA smear + PE on K; writes packed K-frag order ----------------
__global__ LB void ema_pe(const u16* __restrict__ Kraw, const float* __restrict__ alpha,
                          u16* __restrict__ Kp) {
  int idx = blockIdx.x * 256 + threadIdx.x;
  int b8  = idx & 7;
  int s   = (idx >> 3) & 2047;
  int bh  = idx >> 14;
  int dk8 = b8 * 8;
  size_t base = ((size_t)bh * 2048 + s) * 64 + dk8;
  us8 kc = *(const us8*)(Kraw + base);
  float kv[8];
#pragma unroll
  for (int j = 0; j < 8; j++) kv[j] = bf2f(kc[j]);
  if (s > 0) {
    us8 kp = *(const us8*)(Kraw + base - 64);
    float aa = alpha[(bh & 15) * 2047 + s - 1];
    float a = 1.0f / (1.0f + __expf(-aa));
#pragma unroll
    for (int j = 0; j < 8; j++) kv[j] = kv[j] * a + bf2f(kp[j]) * (1.0f - a);
  }
  us8 o;
#pragma unroll
  for (int j = 0; j < 8; j++) o[j] = f2bf(kv[j] + pe_val(s, dk8 + j));
  int kt16 = s >> 4, c = b8 >> 2, quad = b8 & 3, l16s = s & 15;
  size_t off = (size_t)bh * (2048 * 64) + (size_t)kt16 * 1024 + (c * 64 + quad * 16 + l16s) * 8;
  *(us8*)(Kp + off) = o;
}

// ---------------- causal attention: 32 q-rows/wave, 4-way split-K ----------------
// Each block owns a 32-row q-group; each wave a quarter of its key range.
// Every K-frag and V-frag load feeds 2 MFMAs (halves L2 traffic vs r14).
// p = exp2(s) (Q pre-scaled; uniform factor cancels in O = sum(pv)/sum(p)).
template<bool MASK>
static __device__ __forceinline__ void attn_step2(
    int kb, const u16* __restrict__ Kt, const u16* __restrict__ Vt,
    const bf8 qf[2][2], f4 acc[2][4], float* lsum, int lane, int quad, int qrel0) {
  const u16* kbase = Kt + (size_t)kb * 4096;
  const u16* vbase = Vt + (size_t)kb * 4096;
  f4 sc[2][4];
#pragma unroll
  for (int h = 0; h < 2; h++)
#pragma unroll
    for (int t = 0; t < 4; t++) sc[h][t] = f4{0.f, 0.f, 0.f, 0.f};
#pragma unroll
  for (int t = 0; t < 4; t++)
#pragma unroll
    for (int c = 0; c < 2; c++) {
      bf8 kf = __builtin_bit_cast(bf8, *(const us8*)(kbase + (t * 2 + c) * 512 + lane * 8));
      sc[0][t] = __builtin_amdgcn_mfma_f32_16x16x32_bf16(kf, qf[0][c], sc[0][t], 0, 0, 0);
      sc[1][t] = __builtin_amdgcn_mfma_f32_16x16x32_bf16(kf, qf[1][c], sc[1][t], 0, 0, 0);
    }
  us4 pf[2][4];
#pragma unroll
  for (int h = 0; h < 2; h++)
#pragma unroll
    for (int t = 0; t < 4; t++) {
      f4 pv;
#pragma unroll
      for (int r = 0; r < 4; r++) {
        float s = sc[h][t][r];
        if (MASK && (t * 16 + quad * 4 + r > qrel0 + h * 16)) s = -1e30f;
        float p = EXP2(s);
        lsum[h] += p;
        pv[r] = p;
      }
      pf[h][t] = pk_bf16x4(pv);
    }
#pragma unroll
  for (int t = 0; t < 4; t++)
#pragma unroll
    for (int dn = 0; dn < 4; dn++) {
      us4 vf = *(const us4*)(vbase + ((t * 4 + dn) * 64 + lane) * 4);
      acc[0][dn] = mfma16(vf, pf[0][t], acc[0][dn]);
      acc[1][dn] = mfma16(vf, pf[1][t], acc[1][dn]);
    }
}

__global__ LB void attn_kernel(const u16* __restrict__ Qb, const u16* __restrict__ Kp,
                               const u16* __restrict__ Vp, u16* __restrict__ Ab) {
  __shared__ float comb[3][64][36];  // 3 publisher waves x [lane][acc32 + lsum2]
  const int tid = threadIdx.x, w = tid >> 6, lane = tid & 63;
  const int l16 = lane & 15, quad = lane >> 4;
  const int idx = blockIdx.x;
  const int bh = idx & 31;
  const int qg = 63 - (idx >> 5);   // heavy-first; 64 32-row q-groups per bh
  const int qw = qg * 32;
  const size_t bhoff = (size_t)bh * (2048 * 64);
  const u16* Kt = Kp + bhoff;
  const u16* Vt = Vp + bhoff;

  bf8 qf[2][2];
#pragma unroll
  for (int h = 0; h < 2; h++)
#pragma unroll
    for (int c = 0; c < 2; c++)
      qf[h][c] = __builtin_bit_cast(bf8,
          *(const us8*)(Qb + bhoff + (size_t)(qw + h * 16 + l16) * 64 + c * 32 + quad * 8));

  f4 acc[2][4];
#pragma unroll
  for (int h = 0; h < 2; h++)
#pragma unroll
    for (int dn = 0; dn < 4; dn++) acc[h][dn] = f4{0.f, 0.f, 0.f, 0.f};
  float lsum[2] = {0.f, 0.f};

  // keys up to qw+31 stay in block qw>>6 (qw%32==0): T steps, last masked.
  const int T   = (qw >> 6) + 1;
  const int kbs = (w * T) >> 2;         // this wave's quarter
  const int kbe = ((w + 1) * T) >> 2;
  const int e_un = (kbe < T - 1) ? kbe : (T - 1);
  for (int kb = kbs; kb < e_un; kb++)
    attn_step2<false>(kb, Kt, Vt, qf, acc, lsum, lane, quad, 0);
  if (kbe == T && kbe > kbs)            // wave 3 owns the diagonal step
    attn_step2<true>(T - 1, Kt, Vt, qf, acc, lsum, lane, quad, qw + l16 - (T - 1) * 64);

  // merge quarters: waves 1..3 publish; wave 0 reduces + stores
  if (w) {
    float* d = &comb[w - 1][lane][0];
#pragma unroll
    for (int h = 0; h < 2; h++)
#pragma unroll
      for (int dn = 0; dn < 4; dn++)
        *(f4*)(d + (h * 4 + dn) * 4) = acc[h][dn];
    d[32] = lsum[0];
    d[33] = lsum[1];
  }
  __syncthreads();
  if (w == 0) {
#pragma unroll
    for (int i = 0; i < 3; i++) {
      const float* s = &comb[i][lane][0];
#pragma unroll
      for (int h = 0; h < 2; h++)
#pragma unroll
        for (int dn = 0; dn < 4; dn++)
          acc[h][dn] += *(const f4*)(s + (h * 4 + dn) * 4);
      lsum[0] += s[32];
      lsum[1] += s[33];
    }
#pragma unroll
    for (int h = 0; h < 2; h++) {
      lsum[h] += __shfl_xor(lsum[h], 16, 64);
      lsum[h] += __shfl_xor(lsum[h], 32, 64);
    }
    const int b = bh >> 4, hd = bh & 15;
#pragma unroll
    for (int h = 0; h < 2; h++) {
      float rinv = 1.0f / lsum[h];
      const int q = qw + h * 16 + l16;
      u16* orow = Ab + ((size_t)(b * 2048 + q)) * 1024 + hd * 64;
#pragma unroll
      for (int dn = 0; dn < 4; dn++) {
        us4 o = pk_bf16x4(f4{acc[h][dn][0] * rinv, acc[h][dn][1] * rinv,
                             acc[h][dn][2] * rinv, acc[h][dn][3] * rinv});
        *(us4*)(orow + dn * 16 + quad * 4) = o;
      }
    }
  }
}

// ---------------- output projection + residual ----------------
__global__ LB void gemm_out(const u16* __restrict__ Ab, const u16* __restrict__ Wob,
                            const float* __restrict__ X, float* __restrict__ Yp) {
  __shared__ u16 Als[128 * 32];
  __shared__ u16 Bls[128 * 32];
  const int tid = threadIdx.x;
  const int m0 = blockIdx.y * 128, n0 = blockIdx.x * 128;
  f4 acc[4][4];
#pragma unroll
  for (int a = 0; a < 4; a++)
#pragma unroll
    for (int b = 0; b < 4; b++) acc[a][b] = f4{0.f, 0.f, 0.f, 0.f};
  gemm_core(Ab, Wob, Als, Bls, m0, n0, tid, acc);

  const int w = tid >> 6, lane = tid & 63;
  const int l16 = lane & 15, quad = lane >> 4;
  const int wm = w & 1, wn = w >> 1;
#pragma unroll
  for (int mt = 0; mt < 4; mt++)
#pragma unroll
    for (int nt = 0; nt < 4; nt++)
#pragma unroll
      for (int r = 0; r < 4; r++) {
        int m = m0 + wm * 64 + mt * 16 + quad * 4 + r;
        int n = n0 + wn * 64 + nt * 16 + l16;
        size_t o = (size_t)m * 1024 + n;
        Yp[o] = acc[mt][nt][r] + X[o];
      }
}

// ---------------- LayerNorm ----------------
__global__ LB void ln_kernel(const float* __restrict__ Y, const float* __restrict__ g,
                             const float* __restrict__ bta, float* __restrict__ out) {
  __shared__ float ls[4], lsq[4];
  const int row = blockIdx.x, tid = threadIdx.x;
  const int w = tid >> 6, lane = tid & 63;
  f4 v = *(const f4*)(Y + (size_t)row * 1024 + tid * 4);
  float s  = v[0] + v[1] + v[2] + v[3];
  float sq = v[0] * v[0] + v[1] * v[1] + v[2] * v[2] + v[3] * v[3];
#pragma unroll
  for (int d = 1; d < 64; d <<= 1) { s += __shfl_xor(s, d, 64); sq += __shfl_xor(sq, d, 64); }
  if (lane == 0) { ls[w] = s; lsq[w] = sq; }
  __syncthreads();
  s  = ls[0] + ls[1] + ls[2] + ls[3];
  sq = lsq[0] + lsq[1] + lsq[2] + lsq[3];
  float mu  = s * (1.0f / 1024.0f);
  float var = sq * (1.0f / 1024.0f) - mu * mu;
  float rs  = rsqrtf(var + 1e-5f);
  f4 o;
#pragma unroll
  for (int j = 0; j < 4; j++) {
    int col = tid * 4 + j;
    o[j] = (v[j] - mu) * rs * g[col] + bta[col];
  }
  *(f4*)(out + (size_t)row * 1024 + tid * 4) = o;
}

extern "C" void kernel_launch(void* const* d_in, const int* in_sizes, int n_in,
                              void* d_out, int out_size, void* d_ws, size_t ws_size,
                              hipStream_t stream) {
  (void)in_sizes; (void)n_in; (void)out_size; (void)ws_size;
  const float* X  = (const float*)d_in[0];
  const float* Wq = (const float*)d_in[1];
  const float* Wk = (const float*)d_in[2];
  const float* Wv = (const float*)d_in[3];
  const float* Wo = (const float*)d_in[4];
  const float* al = (const float*)d_in[5];
  const float* g  = (const float*)d_in[6];
  const float* bt = (const float*)d_in[7];

  char* ws = (char*)d_ws;
  float* Yp   = (float*)(ws);
  u16*   Xb   = (u16*)(ws + ((size_t)16 << 20));
  u16*   Wcat = (u16*)(ws + ((size_t)24 << 20));
  u16*   Wob  = (u16*)(ws + ((size_t)30 << 20));
  u16*   Qb   = (u16*)(ws + ((size_t)32 << 20));
  u16*   Kraw = (u16*)(ws + ((size_t)40 << 20));
  u16*   Ab   = (u16*)(ws + ((size_t)40 << 20));  // reuses Kraw
  u16*   Kp   = (u16*)(ws + ((size_t)48 << 20));
  u16*   Vp   = (u16*)(ws + ((size_t)56 << 20));

  cvt_kernel<<<dim3(4096), 256, 0, stream>>>(X, Wq, Wk, Wv, Wo, Xb, Wcat, Wob);
  gemm_qkv<<<dim3(24, 32), 256, 0, stream>>>(Xb, Wcat, Qb, Kraw, Vp);
  ema_pe<<<dim3(2048), 256, 0, stream>>>(Kraw, al, Kp);
  attn_kernel<<<dim3(2048), 256, 0, stream>>>(Qb, Kp, Vp, Ab);
  gemm_out<<<dim3(8, 32), 256, 0, stream>>>(Ab, Wob, X, Yp);
  ln_kernel<<<dim3(4096), 256, 0, stream>>>(Yp, g, bt, (float*)d_out);
}

// Round 16
// 211.355 us; speedup vs baseline: 1.1350x; 1.1350x over previous
//
#include <hip/hip_runtime.h>

// Inputs/outputs fp32; internal compute bf16 MFMA (bf16-grade comparison).
// ws layout (64 MB):
//   [0,16M)   Yp    fp32 [B,S,D]
//   [16M,24M) Xb    bf16 [B*S, D]
//   [24M,30M) Wcat  bf16 [3072,1024]
//   [30M,32M) Wob   bf16 [1024,1024]
//   [32M,40M) Qb    bf16 [B,H,S,DK] (post-PE, pre-scaled by 0.125/ln2)
//   [40M,48M) Kraw  bf16 [B,H,S,DK] -> reused as Ab bf16 [B,S,D] after ema_pe
//   [48M,56M) Kp    bf16 packed K-frag order [bh][kt16][c][lane][j8]
//   [56M,64M) Vp    bf16 packed V^T-frag order [bh][kb64][t*4+dn][lane][j4]

#define LB __launch_bounds__(256)
// r6/r8/r15 lesson: NO min-waves hint, NO 2-q-tile register footprint on attn
// (both push VGPRs into the regime where the compiler serializes load batches).
// r10 lesson: NO loop-carried MFMA accumulator chains.
// r14 lesson: attn VALU is not binding; r11's structure is the plateau (~60us).

typedef unsigned short u16;
typedef unsigned int u32;
typedef __attribute__((ext_vector_type(2))) unsigned int u32x2;
typedef __attribute__((ext_vector_type(4))) unsigned short us4;
typedef __attribute__((ext_vector_type(8))) unsigned short us8;
typedef __attribute__((ext_vector_type(8))) __bf16 bf8;
typedef __attribute__((ext_vector_type(4))) float f4;
typedef __attribute__((ext_vector_type(4))) short s4;

// softmax scale folded into Q: exp(s/8) = exp2(s * 0.125/ln2)
#define QSCALE 0.18033688011112042f

#if __has_builtin(__builtin_amdgcn_exp2f)
#define EXP2 __builtin_amdgcn_exp2f   // raw v_exp_f32 (r14-validated: args never denormal)
#else
#define EXP2 exp2f
#endif

static __device__ __forceinline__ float bf2f(u16 h) {
  union { unsigned int u; float f; } c; c.u = ((unsigned int)h) << 16; return c.f;
}
static __device__ __forceinline__ u16 f2bf(float f) {
  union { float f; unsigned int u; } c; c.f = f;
  unsigned int u = c.u + 0x7FFFu + ((c.u >> 16) & 1u);
  return (u16)(u >> 16);
}
// pack 4 fp32 -> 4 bf16 (RNE); packed HW cvt when available
#if __has_builtin(__builtin_amdgcn_cvt_pk_bf16_f32)
typedef __attribute__((ext_vector_type(2))) __bf16 bf2v;
static __device__ __forceinline__ us4 pk_bf16x4(f4 v) {
  bf2v lo = __builtin_amdgcn_cvt_pk_bf16_f32(v[0], v[1]);
  bf2v hi = __builtin_amdgcn_cvt_pk_bf16_f32(v[2], v[3]);
  u32x2 r = {__builtin_bit_cast(u32, lo), __builtin_bit_cast(u32, hi)};
  return __builtin_bit_cast(us4, r);
}
#else
static __device__ __forceinline__ us4 pk_bf16x4(f4 v) {
  return us4{f2bf(v[0]), f2bf(v[1]), f2bf(v[2]), f2bf(v[3])};
}
#endif
static __device__ __forceinline__ float pe_val(int s, int dk) {
  float fr = __expf((float)(dk & ~1) * (-9.210340371976184f / 64.0f));
  float ang = (float)s * fr;
  return (dk & 1) ? __cosf(ang) : __sinf(ang);
}

// 16x16x16 bf16 MFMA, hedged across builtin generations (verified r5).
#if __has_builtin(__builtin_amdgcn_mfma_f32_16x16x16bf16_1k)
static __device__ __forceinline__ f4 mfma16(us4 a, us4 b, f4 c) {
  return __builtin_amdgcn_mfma_f32_16x16x16bf16_1k(
      __builtin_bit_cast(s4, a), __builtin_bit_cast(s4, b), c, 0, 0, 0);
}
#elif __has_builtin(__builtin_amdgcn_mfma_f32_16x16x16_bf16)
typedef __attribute__((ext_vector_type(4))) __bf16 bf4;
static __device__ __forceinline__ f4 mfma16(us4 a, us4 b, f4 c) {
  return __builtin_amdgcn_mfma_f32_16x16x16_bf16(
      __builtin_bit_cast(bf4, a), __builtin_bit_cast(bf4, b), c, 0, 0, 0);
}
#else
static __device__ __forceinline__ f4 mfma16(us4 a, us4 b, f4 c) {
  asm volatile("v_mfma_f32_16x16x16_bf16 %0, %1, %2, %0" : "+v"(c) : "v"(a), "v"(b));
  return c;
}
#endif

#define GLDS(gp, lp) __builtin_amdgcn_global_load_lds( \
    (const __attribute__((address_space(1))) void*)(gp), \
    (__attribute__((address_space(3))) void*)(lp), 16, 0, 0)

// ---------------- fp32 -> bf16 conversion pre-pass ----------------
__global__ LB void cvt_kernel(const float* __restrict__ X, const float* __restrict__ Wq,
                              const float* __restrict__ Wk, const float* __restrict__ Wv,
                              const float* __restrict__ Wo, u16* __restrict__ Xb,
                              u16* __restrict__ Wcat, u16* __restrict__ Wob) {
  const unsigned t = blockIdx.x * 256 + threadIdx.x;
  const float* src; u16* dst; size_t off;
  if (t < (512u << 10))      { src = X;  dst = Xb;                off = t; }
  else if (t < (640u << 10)) { src = Wq; dst = Wcat;              off = t - (512u << 10); }
  else if (t < (768u << 10)) { src = Wk; dst = Wcat + (1u << 20); off = t - (640u << 10); }
  else if (t < (896u << 10)) { src = Wv; dst = Wcat + (2u << 20); off = t - (768u << 10); }
  else                       { src = Wo; dst = Wob;               off = t - (896u << 10); }
  off *= 8;
  f4 a = *(const f4*)(src + off);
  f4 b = *(const f4*)(src + off + 4);
  us8 o = {f2bf(a[0]), f2bf(a[1]), f2bf(a[2]), f2bf(a[3]),
           f2bf(b[0]), f2bf(b[1]), f2bf(b[2]), f2bf(b[3])};
  *(us8*)(dst + off) = o;
}

// ---------------- m97-style GEMM core ----------------
static __device__ __forceinline__ void gemm_core(
    const u16* __restrict__ Abase, const u16* __restrict__ Bbase,
    u16* Als, u16* Bls, int m0, int n0, int tid, f4 acc[4][4]) {
  const int w = tid >> 6, lane = tid & 63;
  const int l16 = lane & 15, quad = lane >> 4;
  const int wm = w & 1, wn = w >> 1;
  for (int kk = 0; kk < 1024; kk += 32) {
    __syncthreads();
#pragma unroll
    for (int it = 0; it < 2; it++) {
      int cb = (w * 2 + it) * 64;
      int c = cb + lane;
      int row = c >> 2, kc = c & 3;
      GLDS(Abase + (size_t)(m0 + row) * 1024 + kk + kc * 8, &Als[cb * 8]);
      GLDS(Bbase + (size_t)(n0 + row) * 1024 + kk + kc * 8, &Bls[cb * 8]);
    }
    __syncthreads();
    bf8 af[4], bfr[4];
#pragma unroll
    for (int mt = 0; mt < 4; mt++)
      af[mt] = __builtin_bit_cast(bf8, *(const us8*)(&Als[(wm * 64 + mt * 16 + l16) * 32 + quad * 8]));
#pragma unroll
    for (int nt = 0; nt < 4; nt++)
      bfr[nt] = __builtin_bit_cast(bf8, *(const us8*)(&Bls[(wn * 64 + nt * 16 + l16) * 32 + quad * 8]));
#pragma unroll
    for (int mt = 0; mt < 4; mt++)
#pragma unroll
      for (int nt = 0; nt < 4; nt++)
        acc[mt][nt] = __builtin_amdgcn_mfma_f32_16x16x32_bf16(af[mt], bfr[nt], acc[mt][nt], 0, 0, 0);
  }
}

// ---------------- QKV projection (fused N=3072) ----------------
__global__ LB void gemm_qkv(const u16* __restrict__ Xb, const u16* __restrict__ Wcat,
                            u16* __restrict__ Qb, u16* __restrict__ Kraw,
                            u16* __restrict__ Vp) {
  __shared__ u16 Als[128 * 32];
  __shared__ u16 Bls[128 * 32];
  const int tid = threadIdx.x;
  const int m0 = blockIdx.y * 128, n0 = blockIdx.x * 128;
  f4 acc[4][4];
#pragma unroll
  for (int a = 0; a < 4; a++)
#pragma unroll
    for (int b = 0; b < 4; b++) acc[a][b] = f4{0.f, 0.f, 0.f, 0.f};
  gemm_core(Xb, Wcat, Als, Bls, m0, n0, tid, acc);

  const int w = tid >> 6, lane = tid & 63;
  const int l16 = lane & 15, quad = lane >> 4;
  const int wm = w & 1, wn = w >> 1;
  const int z = blockIdx.x >> 3;  // 0:Q 1:K 2:V
#pragma unroll
  for (int mt = 0; mt < 4; mt++)
#pragma unroll
    for (int nt = 0; nt < 4; nt++)
#pragma unroll
      for (int r = 0; r < 4; r++) {
        int m = m0 + wm * 64 + mt * 16 + quad * 4 + r;
        int nn = (n0 + wn * 64 + nt * 16 + l16) & 1023;
        float v = acc[mt][nt][r];
        int b = m >> 11, s = m & 2047, h = nn >> 6, dk = nn & 63;
        size_t bhoff = (size_t)(b * 16 + h) * (2048 * 64);
        if (z == 0) {
          // pre-scale Q: scores exit QK^T already in exp2 domain
          Qb[bhoff + (size_t)s * 64 + dk] = f2bf((v + pe_val(s, dk)) * QSCALE);
        } else if (z == 1) {
          Kraw[bhoff + (size_t)s * 64 + dk] = f2bf(v);
        } else {
          // packed V^T-frag order: [kb64][(t*4+dn)][Q*16+l16 (=lane)][j]
          int kb = s >> 6, sl = s & 63;
          int t = sl >> 4, Qq = (sl >> 2) & 3, jj = sl & 3;
          int dn = dk >> 4, lv = dk & 15;
          Vp[bhoff + (size_t)kb * 4096 + ((t * 4 + dn) * 64 + Qq * 16 + lv) * 4 + jj] = f2bf(v);
        }
      }
}

// ---------------- EMA smear + PE on K; writes packed K-frag order ----------------
__global__ LB void ema_pe(const u16* __restrict__ Kraw, const float* __restrict__ alpha,
                          u16* __restrict__ Kp) {
  int idx = blockIdx.x * 256 + threadIdx.x;
  int b8  = idx & 7;
  int s   = (idx >> 3) & 2047;
  int bh  = idx >> 14;
  int dk8 = b8 * 8;
  size_t base = ((size_t)bh * 2048 + s) * 64 + dk8;
  us8 kc = *(const us8*)(Kraw + base);
  float kv[8];
#pragma unroll
  for (int j = 0; j < 8; j++) kv[j] = bf2f(kc[j]);
  if (s > 0) {
    us8 kp = *(const us8*)(Kraw + base - 64);
    float aa = alpha[(bh & 15) * 2047 + s - 1];
    float a = 1.0f / (1.0f + __expf(-aa));
#pragma unroll
    for (int j = 0; j < 8; j++) kv[j] = kv[j] * a + bf2f(kp[j]) * (1.0f - a);
  }
  us8 o;
#pragma unroll
  for (int j = 0; j < 8; j++) o[j] = f2bf(kv[j] + pe_val(s, dk8 + j));
  int kt16 = s >> 4, c = b8 >> 2, quad = b8 & 3, l16s = s & 15;
  size_t off = (size_t)bh * (2048 * 64) + (size_t)kt16 * 1024 + (c * 64 + quad * 16 + l16s) * 8;
  *(us8*)(Kp + off) = o;
}

// ---------------- causal attention: 2-way split-K, L1-paired q-tiles ----------------
// 16 q-rows/wave; waves 0,1 = two q-tiles x key half 0; waves 2,3 = key half 1.
// Paired waves read identical K/V streams -> second reader hits L1.
// p = exp2(s) with Q pre-scaled (uniform factor cancels in O = sum(pv)/sum(p)).
template<bool MASK>
static __device__ __forceinline__ void attn_step(
    int kb, const u16* __restrict__ Kt, const u16* __restrict__ Vt,
    const bf8* qf, f4* acc, float& lsum, int lane, int quad, int qrel0) {
  const u16* kbase = Kt + (size_t)kb * 4096;
  const u16* vbase = Vt + (size_t)kb * 4096;
  f4 sc[4];
#pragma unroll
  for (int t = 0; t < 4; t++) sc[t] = f4{0.f, 0.f, 0.f, 0.f};
#pragma unroll
  for (int t = 0; t < 4; t++)
#pragma unroll
    for (int c = 0; c < 2; c++) {
      bf8 kf = __builtin_bit_cast(bf8, *(const us8*)(kbase + (t * 2 + c) * 512 + lane * 8));
      sc[t] = __builtin_amdgcn_mfma_f32_16x16x32_bf16(kf, qf[c], sc[t], 0, 0, 0);
    }
  us4 pf[4];
#pragma unroll
  for (int t = 0; t < 4; t++) {
    f4 pv;
#pragma unroll
    for (int r = 0; r < 4; r++) {
      float s = sc[t][r];
      if (MASK && (t * 16 + quad * 4 + r > qrel0)) s = -1e30f;
      float p = EXP2(s);          // raw v_exp_f32
      lsum += p;
      pv[r] = p;
    }
    pf[t] = pk_bf16x4(pv);
  }
#pragma unroll
  for (int t = 0; t < 4; t++)
#pragma unroll
    for (int dn = 0; dn < 4; dn++) {
      us4 vf = *(const us4*)(vbase + ((t * 4 + dn) * 64 + lane) * 4);
      acc[dn] = mfma16(vf, pf[t], acc[dn]);
    }
}

__global__ LB void attn_kernel(const u16* __restrict__ Qb, const u16* __restrict__ Kp,
                               const u16* __restrict__ Vp, u16* __restrict__ Ab) {
  __shared__ float comb[2][64][20];  // [qt][lane][acc16 + lsum], 80B stride
  const int tid = threadIdx.x, w = tid >> 6, lane = tid & 63;
  const int l16 = lane & 15, quad = lane >> 4;
  const int idx = blockIdx.x;
  const int bh = idx & 31;
  const int qg = 63 - (idx >> 5);   // heavy-first q-group (32 rows)
  const int qt = w & 1;             // q-tile within group
  const int h2 = w >> 1;            // key half
  const int qw = qg * 32 + qt * 16;
  const size_t bhoff = (size_t)bh * (2048 * 64);
  const u16* Kt = Kp + bhoff;
  const u16* Vt = Vp + bhoff;

  bf8 qf[2];
#pragma unroll
  for (int c = 0; c < 2; c++)
    qf[c] = __builtin_bit_cast(bf8, *(const us8*)(Qb + bhoff + (size_t)(qw + l16) * 64 + c * 32 + quad * 8));

  f4 acc[4];
#pragma unroll
  for (int dn = 0; dn < 4; dn++) acc[dn] = f4{0.f, 0.f, 0.f, 0.f};
  float lsum = 0.f;

  const int T  = (qw >> 6) + 1;      // total 64-key steps (last one masked)
  const int Th = (T + 1) >> 1;       // split point
  const int kbs = h2 ? Th : 0;
  const int kbe = h2 ? T : Th;
  const int e_un = (kbe < T - 1) ? kbe : (T - 1);  // unmasked end
  for (int kb = kbs; kb < e_un; kb++)
    attn_step<false>(kb, Kt, Vt, qf, acc, lsum, lane, quad, 0);
  if (kbe == T && kbe > kbs)         // this wave owns the diagonal step
    attn_step<true>(T - 1, Kt, Vt, qf, acc, lsum, lane, quad, qw + l16 - (T - 1) * 64);

  // merge halves: waves 2,3 publish; waves 0,1 reduce + store
  if (h2) {
    float* d = &comb[qt][lane][0];
    *(f4*)(d)      = acc[0];
    *(f4*)(d + 4)  = acc[1];
    *(f4*)(d + 8)  = acc[2];
    *(f4*)(d + 12) = acc[3];
    d[16] = lsum;
  }
  __syncthreads();
  if (!h2) {
    const float* s = &comb[qt][lane][0];
    acc[0] += *(const f4*)(s);
    acc[1] += *(const f4*)(s + 4);
    acc[2] += *(const f4*)(s + 8);
    acc[3] += *(const f4*)(s + 12);
    lsum += s[16];
    lsum += __shfl_xor(lsum, 16, 64);
    lsum += __shfl_xor(lsum, 32, 64);
    float rinv = 1.0f / lsum;
    const int b = bh >> 4, h = bh & 15;
    const int q = qw + l16;
    u16* orow = Ab + ((size_t)(b * 2048 + q)) * 1024 + h * 64;
#pragma unroll
    for (int dn = 0; dn < 4; dn++) {
      us4 o = pk_bf16x4(f4{acc[dn][0] * rinv, acc[dn][1] * rinv,
                           acc[dn][2] * rinv, acc[dn][3] * rinv});
      *(us4*)(orow + dn * 16 + quad * 4) = o;
    }
  }
}

// ---------------- output projection + residual ----------------
__global__ LB void gemm_out(const u16* __restrict__ Ab, const u16* __restrict__ Wob,
                            const float* __restrict__ X, float* __restrict__ Yp) {
  __shared__ u16 Als[128 * 32];
  __shared__ u16 Bls[128 * 32];
  const int tid = threadIdx.x;
  const int m0 = blockIdx.y * 128, n0 = blockIdx.x * 128;
  f4 acc[4][4];
#pragma unroll
  for (int a = 0; a < 4; a++)
#pragma unroll
    for (int b = 0; b < 4; b++) acc[a][b] = f4{0.f, 0.f, 0.f, 0.f};
  gemm_core(Ab, Wob, Als, Bls, m0, n0, tid, acc);

  const int w = tid >> 6, lane = tid & 63;
  const int l16 = lane & 15, quad = lane >> 4;
  const int wm = w & 1, wn = w >> 1;
#pragma unroll
  for (int mt = 0; mt < 4; mt++)
#pragma unroll
    for (int nt = 0; nt < 4; nt++)
#pragma unroll
      for (int r = 0; r < 4; r++) {
        int m = m0 + wm * 64 + mt * 16 + quad * 4 + r;
        int n = n0 + wn * 64 + nt * 16 + l16;
        size_t o = (size_t)m * 1024 + n;
        Yp[o] = acc[mt][nt][r] + X[o];
      }
}

// ---------------- LayerNorm ----------------
__global__ LB void ln_kernel(const float* __restrict__ Y, const float* __restrict__ g,
                             const float* __restrict__ bta, float* __restrict__ out) {
  __shared__ float ls[4], lsq[4];
  const int row = blockIdx.x, tid = threadIdx.x;
  const int w = tid >> 6, lane = tid & 63;
  f4 v = *(const f4*)(Y + (size_t)row * 1024 + tid * 4);
  float s  = v[0] + v[1] + v[2] + v[3];
  float sq = v[0] * v[0] + v[1] * v[1] + v[2] * v[2] + v[3] * v[3];
#pragma unroll
  for (int d = 1; d < 64; d <<= 1) { s += __shfl_xor(s, d, 64); sq += __shfl_xor(sq, d, 64); }
  if (lane == 0) { ls[w] = s; lsq[w] = sq; }
  __syncthreads();
  s  = ls[0] + ls[1] + ls[2] + ls[3];
  sq = lsq[0] + lsq[1] + lsq[2] + lsq[3];
  float mu  = s * (1.0f / 1024.0f);
  float var = sq * (1.0f / 1024.0f) - mu * mu;
  float rs  = rsqrtf(var + 1e-5f);
  f4 o;
#pragma unroll
  for (int j = 0; j < 4; j++) {
    int col = tid * 4 + j;
    o[j] = (v[j] - mu) * rs * g[col] + bta[col];
  }
  *(f4*)(out + (size_t)row * 1024 + tid * 4) = o;
}

extern "C" void kernel_launch(void* const* d_in, const int* in_sizes, int n_in,
                              void* d_out, int out_size, void* d_ws, size_t ws_size,
                              hipStream_t stream) {
  (void)in_sizes; (void)n_in; (void)out_size; (void)ws_size;
  const float* X  = (const float*)d_in[0];
  const float* Wq = (const float*)d_in[1];
  const float* Wk = (const float*)d_in[2];
  const float* Wv = (const float*)d_in[3];
  const float* Wo = (const float*)d_in[4];
  const float* al = (const float*)d_in[5];
  const float* g  = (const float*)d_in[6];
  const float* bt = (const float*)d_in[7];

  char* ws = (char*)d_ws;
  float* Yp   = (float*)(ws);
  u16*   Xb   = (u16*)(ws + ((size_t)16 << 20));
  u16*   Wcat = (u16*)(ws + ((size_t)24 << 20));
  u16*   Wob  = (u16*)(ws + ((size_t)30 << 20));
  u16*   Qb   = (u16*)(ws + ((size_t)32 << 20));
  u16*   Kraw = (u16*)(ws + ((size_t)40 << 20));
  u16*   Ab   = (u16*)(ws + ((size_t)40 << 20));  // reuses Kraw
  u16*   Kp   = (u16*)(ws + ((size_t)48 << 20));
  u16*   Vp   = (u16*)(ws + ((size_t)56 << 20));

  cvt_kernel<<<dim3(4096), 256, 0, stream>>>(X, Wq, Wk, Wv, Wo, Xb, Wcat, Wob);
  gemm_qkv<<<dim3(24, 32), 256, 0, stream>>>(Xb, Wcat, Qb, Kraw, Vp);
  ema_pe<<<dim3(2048), 256, 0, stream>>>(Kraw, al, Kp);
  attn_kernel<<<dim3(2048), 256, 0, stream>>>(Qb, Kp, Vp, Ab);
  gemm_out<<<dim3(8, 32), 256, 0, stream>>>(Ab, Wob, X, Yp);
  ln_kernel<<<dim3(4096), 256, 0, stream>>>(Yp, g, bt, (float*)d_out);
}